// Round 17
// baseline (235.956 us; speedup 1.0000x reference)
//
#include <hip/hip_runtime.h>
#include <hip/hip_bf16.h>

#define DI __device__ __forceinline__

typedef __bf16 bf16x8 __attribute__((ext_vector_type(8)));
typedef float  f32x4  __attribute__((ext_vector_type(4)));
typedef float  f32x16 __attribute__((ext_vector_type(16)));

DI unsigned short f2bf(float f) {
    unsigned int u = __float_as_uint(f);
    u += 0x7fffu + ((u >> 16) & 1u);
    return (unsigned short)(u >> 16);
}

DI void gload16(const unsigned short* g, unsigned short* l) {
    __builtin_amdgcn_global_load_lds(
        (const __attribute__((address_space(1))) unsigned int*)g,
        (__attribute__((address_space(3))) unsigned int*)l, 16, 0, 0);
}

// ---------------------------------------------------------------------------
__global__ void convert_x(const float* __restrict__ x, unsigned short* __restrict__ Xb) {
    int i = blockIdx.x * 256 + threadIdx.x;
    float4 v = reinterpret_cast<const float4*>(x)[i];
    ushort4 o;
    o.x = f2bf(v.x); o.y = f2bf(v.y); o.z = f2bf(v.z); o.w = f2bf(v.w);
    reinterpret_cast<ushort4*>(Xb)[i] = o;
}

__global__ void convert_w(const float* __restrict__ Wq, const float* __restrict__ Wk,
                          const float* __restrict__ Wv, unsigned short* __restrict__ Wt) {
    __shared__ float t[32][33];
    const int z = blockIdx.z;
    const float* W = (z == 0) ? Wq : (z == 1 ? Wk : Wv);
    const float scale = (z == 0) ? 0.03125f : 1.0f;
    const int n0 = blockIdx.x * 32, k0 = blockIdx.y * 32;
    const int tx = threadIdx.x, ty = threadIdx.y;
#pragma unroll
    for (int i = 0; i < 4; ++i)
        t[ty + i * 8][tx] = W[(size_t)(k0 + ty + i * 8) * 1024 + n0 + tx];
    __syncthreads();
#pragma unroll
    for (int i = 0; i < 4; ++i)
        Wt[(size_t)(z * 1024 + n0 + ty + i * 8) * 1024 + k0 + tx] =
            f2bf(t[tx][ty + i * 8] * scale);
}

#define BAR    asm volatile("s_barrier" ::: "memory")
#define WAITV4 asm volatile("s_waitcnt vmcnt(4)" ::: "memory")
#define WAITV3 asm volatile("s_waitcnt vmcnt(3)" ::: "memory")
#define WAITV0 asm volatile("s_waitcnt vmcnt(0)" ::: "memory")

// ---------------------------------------------------------------------------
// gemm256 ROUND 17: round-4 schedule skeleton (FROZEN: stages, barriers,
// vmcnt identical) with the MFMA shape swapped 16x16x32 -> 32x32x16
// (µbench 2495 vs 2075 TF => ~15% less matrix-pipe time; MFMA count halves).
// LDS traffic invariant (24 b128/wave/kt). Fragment layouts:
//   A/B: row(col)=lane&31, k=(lane>>5)*8+e  (k-octet analog of 16x16 path)
//   C/D: col=lane&31, row=(reg&3)+8*(reg>>2)+4*(lane>>5)  [m74/m101]
// Reader chunk for kstep s: (2s+hi)^(row&7) vs the unchanged swizzle writer.
// ---------------------------------------------------------------------------

#define READ_A32(SLOT, MH)                                                    \
    _Pragma("unroll")                                                         \
    for (int f2_ = 0; f2_ < 2; ++f2_)                                         \
        _Pragma("unroll")                                                     \
        for (int s_ = 0; s_ < 4; ++s_)                                        \
            aF[f2_][s_] = *reinterpret_cast<const bf16x8*>(                   \
                lsA + ((SLOT) * 2 + (MH)) * 8192 + abase32 + f2_ * 2048 +     \
                koffs[s_]);

#define READ_B32(SLOT, NH, BS)                                                \
    _Pragma("unroll")                                                         \
    for (int s_ = 0; s_ < 4; ++s_)                                            \
        BS[s_] = *reinterpret_cast<const bf16x8*>(                            \
            lsB + ((SLOT) * 2 + (NH)) * 8192 + bbase32 + koffs[s_]);

#define STAGE_A(KT, H)                                                        \
    {                                                                         \
        unsigned uA_ = (unsigned)(m0 + (H) * 128) * 1024u + (unsigned)(KT) * 64u; \
        _Pragma("unroll")                                                     \
        for (int it = 0; it < 2; ++it)                                        \
            gload16(Ab + uA_ + sAoff[it],                                     \
                    lsA + (((KT) & 1) * 2 + (H)) * 8192 + it * 4096 + tid * 8);\
    }

#define STAGE_B(KT, H)                                                        \
    {                                                                         \
        unsigned uB_ = (unsigned)(n0 + (H) * 128) * 1024u + (unsigned)(KT) * 64u; \
        _Pragma("unroll")                                                     \
        for (int it = 0; it < 2; ++it)                                        \
            gload16(Bb + uB_ + sBoff[it],                                     \
                    lsB + (((KT) & 1) * 2 + (H)) * 8192 + it * 4096 + tid * 8);\
    }

#define MMA32(MH, NH, BS)                                                     \
    __builtin_amdgcn_s_setprio(1);                                            \
    _Pragma("unroll")                                                         \
    for (int s_ = 0; s_ < 4; ++s_)                                            \
        _Pragma("unroll")                                                     \
        for (int f2_ = 0; f2_ < 2; ++f2_)                                     \
            acc[(MH) * 2 + f2_][NH] = __builtin_amdgcn_mfma_f32_32x32x16_bf16(\
                aF[f2_][s_], BS[s_], acc[(MH) * 2 + f2_][NH], 0, 0, 0);       \
    __builtin_amdgcn_s_setprio(0);

__global__ __launch_bounds__(512, 2) void gemm256(
    const unsigned short* __restrict__ A0, const unsigned short* __restrict__ B0,
    unsigned short* __restrict__ Oq, unsigned short* __restrict__ Ok,
    unsigned short* __restrict__ Ov)
{
    extern __shared__ char smem_raw[];
    unsigned short* lsA = (unsigned short*)smem_raw;
    unsigned short* lsB = lsA + 32768;

    const int tid = threadIdx.x;
    const int lane = tid & 63;
    const int wid = tid >> 6;
    const int wm = wid >> 2, wn = wid & 3;
    const int l31 = lane & 31, hi = lane >> 5;

    const int m0 = blockIdx.x * 256, n0 = blockIdx.y * 256;
    const int NT = 16;
    const unsigned short* Ab = A0;
    const unsigned short* Bb = B0;

    // fragment read bases (elements within a 128x64 half) + per-kstep chunks
    const unsigned m7 = (unsigned)(l31 & 7);
    const unsigned abase32 = (unsigned)(wm * 64 + l31) * 64u;
    const unsigned bbase32 = (unsigned)(wn * 32 + l31) * 64u;
    unsigned koffs[4];
#pragma unroll
    for (int s = 0; s < 4; ++s)
        koffs[s] = (((unsigned)(2 * s + hi)) ^ m7) * 8u;

    // stage source offsets (swizzle writer identical to rounds 4-16)
    unsigned sAoff[2], sBoff[2];
#pragma unroll
    for (int it = 0; it < 2; ++it) {
        const unsigned idx = it * 512 + tid;
        const unsigned row = idx >> 3;
        const unsigned ch = (idx & 7) ^ (row & 7);
        sAoff[it] = row * 1024u + ch * 8u;
        sBoff[it] = row * 1024u + ch * 8u;
    }

    f32x16 acc[4][2] = {};
    bf16x8 aF[2][4], bF0[4], bF1[4];

    STAGE_A(0, 0); STAGE_A(0, 1); STAGE_B(0, 0); STAGE_B(0, 1);
    STAGE_A(1, 0); STAGE_B(1, 0);
    WAITV4; BAR;

    for (int kt = 0; kt < NT; ++kt) {
        const int slot = kt & 1;
        const bool s1 = (kt + 1) < NT, s2 = (kt + 2) < NT;
        READ_A32(slot, 0); READ_B32(slot, 0, bF0);
        if (s1) { STAGE_A(kt + 1, 1); }
        BAR; MMA32(0, 0, bF0);
        READ_B32(slot, 1, bF1);
        if (s1) { STAGE_B(kt + 1, 1); }
        BAR; MMA32(0, 1, bF1);
        READ_A32(slot, 1);
        if (s2) { STAGE_A(kt + 2, 0); }
        BAR; MMA32(1, 0, bF0);
        if (s2) {
            STAGE_B(kt + 2, 0);
            WAITV4;
        } else {
            WAITV0;
        }
        BAR; MMA32(1, 1, bF1);
    }

    // epilogue: 32x32 D layout col=l31, row=(reg&3)+8*(reg>>2)+4*hi
#pragma unroll
    for (int mh = 0; mh < 2; ++mh)
#pragma unroll
    for (int f2 = 0; f2 < 2; ++f2)
#pragma unroll
    for (int nh = 0; nh < 2; ++nh) {
        f32x16 v = acc[mh * 2 + f2][nh];
        const int gmb = m0 + mh * 128 + wm * 64 + f2 * 32 + 4 * hi;
        const int cl = nh * 128 + wn * 32 + l31;
        const int z = n0 >> 10;
        const int cin = (n0 & 1023) + cl;
        if (z == 2) {   // V stored transposed per batch: Vt[b][d][n]
            const int b = gmb >> 11;
#pragma unroll
            for (int r4 = 0; r4 < 4; ++r4) {
                const int nib = (gmb + 8 * r4) & 2047;
                ushort4 h;
                h.x = f2bf(v[r4 * 4 + 0]); h.y = f2bf(v[r4 * 4 + 1]);
                h.z = f2bf(v[r4 * 4 + 2]); h.w = f2bf(v[r4 * 4 + 3]);
                *reinterpret_cast<ushort4*>(
                    &Ov[(size_t)b * 2097152u + (size_t)cin * 2048 + nib]) = h;
            }
        } else {
            unsigned short* O = z ? Ok : Oq;
#pragma unroll
            for (int reg = 0; reg < 16; ++reg)
                O[(size_t)(gmb + (reg & 3) + 8 * (reg >> 2)) * 1024 + cin] =
                    f2bf(v[reg]);
        }
    }
}

// ---------------------------------------------------------------------------
// Attention GEMMs — ROUND 16 VERSION, BYTE-IDENTICAL (passing, absmax 0.0195).
// MODE 1: S=Q@K^T, epilogue causal-mask+exp, bf16 P~ out (exp once/element).
// MODE 2: pure GEMM on P~; den via ones-MFMA (same acc layout, epilogue div).
// ---------------------------------------------------------------------------
template <int MODE>
__global__ __launch_bounds__(512, 4) void gemm_attn(
    const unsigned short* __restrict__ A0, const unsigned short* __restrict__ B0,
    void* __restrict__ Cf0)
{
    __shared__ alignas(16) unsigned short lds[3 * 12288];  // slot: A 4096 + B 8192 elems

    const int tid = threadIdx.x;
    const int lane = tid & 63;
    const int wid = tid >> 6;
    const int wm = wid >> 2, wn = wid & 3;
    const int lr = lane & 15, lg = lane >> 4;

    int r128, n0, NT, bz;
    constexpr unsigned STRB = (MODE == 2) ? 2048u : 1024u;

    if constexpr (MODE == 1) {
        const int idx = blockIdx.x;          // 1024 linear: bz-major for XCD pin
        bz = idx & 7;
        r128 = (idx >> 3) & 15;
        const int c256 = idx >> 7;           // 0..7
        if (c256 > (r128 >> 1)) return;
        n0 = c256 * 256; NT = 32;
    } else {
        const int idx = blockIdx.x;          // 512 blocks, complementary pairing
        const int k5 = idx >> 5;             // 0..15
        r128 = (k5 < 8) ? (15 - k5) : (k5 - 8);
        const int nt4 = (idx >> 3) & 3;
        bz = idx & 7;
        n0 = nt4 * 256; NT = 4 * (r128 + 1);
    }
    const int r256 = r128 >> 1;
    const unsigned short* Bb = B0 + (size_t)bz * 2097152u;

    const unsigned short* Ab;
    size_t cbase;
    if constexpr (MODE == 1) {
        Ab = A0 + (size_t)bz * 2097152u;
        cbase = ((size_t)bz * 36 + (size_t)(r256 * (r256 + 1) / 2) + (n0 >> 8)) * 65536u +
                (size_t)(r128 & 1) * 32768u;
    } else {
        Ab = A0 + ((size_t)bz * 36 + (size_t)(r256 * (r256 + 1) / 2)) * 65536u;
        cbase = (size_t)bz * 2097152u + (size_t)(r128 * 128) * 1024u;
    }

    const unsigned fswl = (unsigned)((lr ^ (lr >> 2)) & 3);
    const unsigned abase = (unsigned)(wm * 64 + lr) * 32u + ((unsigned)lg ^ fswl) * 8u;
    const unsigned bbase = 4096u + (unsigned)(wn * 32 + lr) * 32u + ((unsigned)lg ^ fswl) * 8u;

    const unsigned rowA = (unsigned)(tid >> 2);
    const unsigned chA = ((unsigned)tid & 3u) ^ (unsigned)((rowA ^ (rowA >> 2)) & 3u);
    unsigned sAoff;
    if constexpr (MODE == 1)
        sAoff = ((unsigned)(r128 * 128) + rowA) * 1024u + chA * 8u;
    else
        sAoff = ((unsigned)((r128 & 1) * 128) + rowA) * 256u + chA * 8u;
    unsigned sBoff[2];
#pragma unroll
    for (int it = 0; it < 2; ++it) {
        const unsigned idx = it * 512 + tid;
        const unsigned rowB = idx >> 2;
        const unsigned chB = (idx & 3u) ^ (unsigned)((rowB ^ (rowB >> 2)) & 3u);
        sBoff[it] = ((unsigned)n0 + rowB) * STRB + chB * 8u;
    }

#define AT_STAGE(KT, SL)                                                      \
    {                                                                         \
        unsigned u_;                                                          \
        if constexpr (MODE == 2)                                              \
            u_ = ((unsigned)((KT) >> 3)) * 65536u + ((KT) & 7) * 32u;         \
        else                                                                  \
            u_ = (unsigned)(KT) * 32u;                                        \
        gload16(Ab + u_ + sAoff, lds + (SL) * 12288 + tid * 8);               \
        gload16(Bb + (unsigned)(KT) * 32u + sBoff[0],                         \
                lds + (SL) * 12288 + 4096 + tid * 8);                         \
        gload16(Bb + (unsigned)(KT) * 32u + sBoff[1],                         \
                lds + (SL) * 12288 + 8192 + tid * 8);                         \
    }

    f32x4 acc[4][4] = {};
    f32x4 accd[4] = {};
    bf16x8 aR[4], bv[2];
    bf16x8 ones;
#pragma unroll
    for (int i = 0; i < 8; ++i) ones[i] = (__bf16)1.0f;

    AT_STAGE(0, 0); AT_STAGE(1, 1);

    int sl = 0, st2 = 2;
    for (int kt = 0; kt < NT; ++kt) {
        if (kt + 1 < NT) { WAITV3; } else { WAITV0; }
        BAR;
        if (kt + 2 < NT) { AT_STAGE(kt + 2, st2); }
        const unsigned short* sp = lds + sl * 12288;
#pragma unroll
        for (int fi = 0; fi < 4; ++fi)
            aR[fi] = *reinterpret_cast<const bf16x8*>(sp + abase + fi * 512);
#pragma unroll
        for (int fj = 0; fj < 2; ++fj)
            bv[fj] = *reinterpret_cast<const bf16x8*>(sp + bbase + fj * 512);
        __builtin_amdgcn_s_setprio(1);
#pragma unroll
        for (int fi = 0; fi < 4; ++fi)
#pragma unroll
            for (int fj = 0; fj < 2; ++fj)
                acc[fi][fj] = __builtin_amdgcn_mfma_f32_16x16x32_bf16(
                    aR[fi], bv[fj], acc[fi][fj], 0, 0, 0);
        __builtin_amdgcn_s_setprio(0);
#pragma unroll
        for (int fj = 0; fj < 2; ++fj)
            bv[fj] = *reinterpret_cast<const bf16x8*>(sp + bbase + 4096 + fj * 512);
        __builtin_amdgcn_s_setprio(1);
#pragma unroll
        for (int fi = 0; fi < 4; ++fi) {
#pragma unroll
            for (int fj = 0; fj < 2; ++fj)
                acc[fi][2 + fj] = __builtin_amdgcn_mfma_f32_16x16x32_bf16(
                    aR[fi], bv[fj], acc[fi][2 + fj], 0, 0, 0);
            if constexpr (MODE == 2)
                accd[fi] = __builtin_amdgcn_mfma_f32_16x16x32_bf16(
                    aR[fi], ones, accd[fi], 0, 0, 0);
        }
        __builtin_amdgcn_s_setprio(0);
        sl = (sl == 2) ? 0 : sl + 1;
        st2 = (st2 == 2) ? 0 : st2 + 1;
    }

    // epilogue: D frag layout col=lr, row=lg*4+r2
    f32x4 rv[4];
    if constexpr (MODE == 2) {
#pragma unroll
        for (int fi = 0; fi < 4; ++fi)
#pragma unroll
            for (int r2 = 0; r2 < 4; ++r2)
                rv[fi][r2] = 1.0f / accd[fi][r2];
    }

#pragma unroll
    for (int fi = 0; fi < 4; ++fi) {
        const int rloc = wm * 64 + fi * 16 + lg * 4;
#pragma unroll
        for (int j = 0; j < 4; ++j) {
            const int cloc = (j >> 1) * 128 + wn * 32 + (j & 1) * 16 + lr;
            f32x4 v = acc[fi][j];
            if constexpr (MODE == 1) {
                unsigned short* Cs = (unsigned short*)Cf0;
                const bool diag = ((n0 >> 8) == r256);
                const int growb = r128 * 128 + rloc;
                const int gcol = n0 + cloc;
#pragma unroll
                for (int r2 = 0; r2 < 4; ++r2) {
                    float e = __expf(v[r2]);
                    if (diag && gcol > growb + r2) e = 0.0f;
                    Cs[cbase + (size_t)(rloc + r2) * 256 + cloc] = f2bf(e);
                }
            } else {
                float* Cf = (float*)Cf0;
#pragma unroll
                for (int r2 = 0; r2 < 4; ++r2)
                    Cf[cbase + (size_t)(rloc + r2) * 1024 + (n0 + cloc)] =
                        v[r2] * rv[fi][r2];
            }
        }
    }
#undef AT_STAGE
}

// ---------------------------------------------------------------------------
extern "C" void kernel_launch(void* const* d_in, const int* in_sizes, int n_in,
                              void* d_out, int out_size, void* d_ws, size_t ws_size,
                              hipStream_t stream) {
    const float* x  = (const float*)d_in[0];
    const float* Wq = (const float*)d_in[1];
    const float* Wk = (const float*)d_in[2];
    const float* Wv = (const float*)d_in[3];
    float* out = (float*)d_out;

    char* base = (char*)d_ws;
    unsigned short* Qb = (unsigned short*)(base);
    unsigned short* Kb = (unsigned short*)(base + 33554432u);
    unsigned short* Vt = (unsigned short*)(base + 67108864u);
    unsigned short* Xb = (unsigned short*)(base + 100663296u);
    unsigned short* Wt = (unsigned short*)(base + 134217728u);
    unsigned short* Sb = (unsigned short*)(base + 100663296u);   // overlays Xb/Wt, 37.7MB

    hipFuncSetAttribute(reinterpret_cast<const void*>(&gemm256),
                        hipFuncAttributeMaxDynamicSharedMemorySize, 131072);

    convert_x<<<16384, 256, 0, stream>>>(x, Xb);
    convert_w<<<dim3(32, 32, 3), dim3(32, 8), 0, stream>>>(Wq, Wk, Wv, Wt);
    gemm256<<<dim3(64, 12), 512, 131072, stream>>>(Xb, Wt, Qb, Kb, Vt);
    gemm_attn<1><<<1024, 512, 0, stream>>>(Qb, Kb, Sb);
    gemm_attn<2><<<512, 512, 0, stream>>>(Sb, Vt, out);
}